// Round 10
// baseline (244.530 us; speedup 1.0000x reference)
//
#include <hip/hip_runtime.h>
#include <cstddef>

// AttentionLayerPooler: out[m,n] = sum_l softmax(logits)[m,l] * in[l,n]
// LT=36, LS=28, slice = 2,097,152 fp32. CU-view traffic 1.07 GB ->
// floor = 1.07 GB / 6.29 TB/s (10.2 B/cyc/CU vector-path ceiling) = 171 us.
//
// R5-R9 all land ~230 us (7.6 B/cyc/CU) across 4 different structures:
// not LDS-pipe (R9 disproved), not vmem-drain (R8 disproved), not
// occupancy (R9 at 39%). Last untested invariant: 2 barriers/tile
// phase-lock the block's 4 waves; load bursts are followed by
// barrier-correlated silence.
// R10: SINGLE-WAVE persistent blocks, ZERO barriers. One wave owns its
// tile end-to-end: 9x global_load_lds (9 KB), 28-acc compute, 28 stores,
// self-paced by counted vmcnt only. 18.4 KB LDS -> 8 independent
// waves/CU, each with ~12 KB in flight.
//   vmcnt ledger (per wave, in-order retire): at the wait in iter t the
//   queue is loads(t)=9 (oldest) + stores(t-1)=28 + loads(t+1)=9 = 46
//   -> vmcnt(37) clears exactly loads(t). Prologue: vmcnt(0) once.
//   Final iter (no prefetch): queue=37 -> vmcnt(28).
// Weights: R9-proven SMEM path (s_load_dwordx4 from d_ws, K$-hot),
// groups of 7 m -> 28 live SGPRs.

constexpr int LT = 36;
constexpr int LS = 28;
constexpr int NELEM = 2097152;          // floats per layer slice
constexpr int TILE_F = 64;              // floats per tile row (256 B)
constexpr int TPT = NELEM / TILE_F;     // 32768 tiles per tensor
constexpr int NTILES = 2 * TPT;         // 65536
constexpr int NBLOCKS = 2048;           // 8 blocks/CU x 256 CU; 32 tiles/block
constexpr int W_STRIDE = 9 * LS * 4;    // 1008 floats per weight table

typedef __attribute__((ext_vector_type(4))) float f32x4;

// Pre-kernel: softmax both 28x36 tables into d_ws, layout
// ws[tensor][l>>2][m][l&3]: quad (m,lb) at byte offset lb*448 + m*16,
// so any 7-m band is 7 s_load_dwordx4 at compile-time offsets.
__global__ __launch_bounds__(64) void softmax_kernel(
    const float* __restrict__ lgk, const float* __restrict__ lgv,
    float* __restrict__ ws)
{
    const int t = threadIdx.x;
    const int isv = t >> 5;
    const int m = t & 31;
    if (m >= LS) return;
    const float* row = (isv ? lgv : lgk) + m * LT;
    float mx = -3.4e38f;
    for (int l = 0; l < LT; ++l) mx = fmaxf(mx, row[l]);
    float s = 0.f;
    for (int l = 0; l < LT; ++l) s += expf(row[l] - mx);
    const float inv = 1.0f / s;
    float* o = ws + isv * W_STRIDE;
    for (int l = 0; l < LT; ++l)
        o[(l >> 2) * (LS * 4) + m * 4 + (l & 3)] = expf(row[l] - mx) * inv;
}

// One (lb, m-group): 7 weight quads via SMEM (28 SGPRs live), 28 FMAs.
template<int LB, int G>
__device__ __forceinline__ void do_grp(const float* wq, const float d[4],
                                       float* acc)
{
    f32x4 w0, w1, w2, w3, w4, w5, w6;
    asm volatile(
        "s_load_dwordx4 %0, %[b], %[o0]\n\t"
        "s_load_dwordx4 %1, %[b], %[o1]\n\t"
        "s_load_dwordx4 %2, %[b], %[o2]\n\t"
        "s_load_dwordx4 %3, %[b], %[o3]\n\t"
        "s_load_dwordx4 %4, %[b], %[o4]\n\t"
        "s_load_dwordx4 %5, %[b], %[o5]\n\t"
        "s_load_dwordx4 %6, %[b], %[o6]\n\t"
        "s_waitcnt lgkmcnt(0)"
        : "=s"(w0), "=s"(w1), "=s"(w2), "=s"(w3), "=s"(w4), "=s"(w5), "=s"(w6)
        : [b] "s"(wq),
          [o0] "i"(LB * 448 + G * 112 + 0),
          [o1] "i"(LB * 448 + G * 112 + 16),
          [o2] "i"(LB * 448 + G * 112 + 32),
          [o3] "i"(LB * 448 + G * 112 + 48),
          [o4] "i"(LB * 448 + G * 112 + 64),
          [o5] "i"(LB * 448 + G * 112 + 80),
          [o6] "i"(LB * 448 + G * 112 + 96));

    const f32x4 W[7] = {w0, w1, w2, w3, w4, w5, w6};
#pragma unroll
    for (int k = 0; k < 7; ++k) {
        float a = acc[7 * G + k];   // compile-time index -> stays in VGPR
        a = fmaf(W[k].x, d[0], a);
        a = fmaf(W[k].y, d[1], a);
        a = fmaf(W[k].z, d[2], a);
        a = fmaf(W[k].w, d[3], a);
        acc[7 * G + k] = a;
    }
}

// One lb-block (4 layers): 4 conflict-free ds_read_b32 (lanes L, L+32 hit
// the same bank at different 128B-offset addrs = free 2-way), 4 m-groups.
template<int LB>
__device__ __forceinline__ void do_lb(const float* wq,
                                      const float (*cur)[TILE_F],
                                      int lane, float* acc)
{
    float d[4];
#pragma unroll
    for (int j = 0; j < 4; ++j) d[j] = cur[4 * LB + j][lane];
    do_grp<LB, 0>(wq, d, acc);
    do_grp<LB, 1>(wq, d, acc);
    do_grp<LB, 2>(wq, d, acc);
    do_grp<LB, 3>(wq, d, acc);
}

__global__ __launch_bounds__(64) void pool_kernel(
    const float* __restrict__ ks,
    const float* __restrict__ vs,
    const float* __restrict__ ws,
    float* __restrict__ out)
{
    // Depth-2 single-wave staging: 2 x 9216 B = 18,432 B -> 8 blocks/CU.
    __shared__ float smA[LT][TILE_F];
    __shared__ float smB[LT][TILE_F];

    const int lane = threadIdx.x;  // single 64-lane wave per block

    // DMA chunk i covers rows 4i..4i+3 (1 KB): lane L -> row 4i+(L>>4),
    // float col 4*(L&15). LDS dest is linear (wave-uniform base + 16L).
    const size_t lofs = (size_t)(lane >> 4) * NELEM + (size_t)((lane & 15) << 2);

    auto stage = [&](float (*buf)[TILE_F], int t) {
        const float* src = (t >= TPT) ? vs : ks;
        const size_t c0 = (size_t)(t & (TPT - 1)) * TILE_F;
#pragma unroll
        for (int i = 0; i < 9; ++i) {
            const float* g = src + (size_t)(4 * i) * NELEM + c0 + lofs;
            __builtin_amdgcn_global_load_lds(
                (const __attribute__((address_space(1))) void*)g,
                (__attribute__((address_space(3))) void*)&buf[4 * i][0],
                16, 0, 0);
        }
    };

    int t = blockIdx.x;
    stage(smA, t);
    asm volatile("s_waitcnt vmcnt(0)" ::: "memory");  // once, prologue only

    float (*cur)[TILE_F] = smA;
    float (*nxt)[TILE_F] = smB;

    for (;;) {
        const int tn = t + NBLOCKS;
        const bool more = (tn < NTILES);

        // A) Prefetch next tile. Safe: our own reads of nxt (as cur of
        //    t-1) finished last iteration (lgkmcnt-forced before FMAs).
        if (more) stage(nxt, tn);

        // B) Counted wait: clear exactly loads(t), keep stores(t-1) and
        //    loads(t+1) in flight. No barrier anywhere.
        if (more) asm volatile("s_waitcnt vmcnt(37)" ::: "memory");
        else      asm volatile("s_waitcnt vmcnt(28)" ::: "memory");
        __builtin_amdgcn_sched_barrier(0);

        const bool isv = (t >= TPT);
        const float* wq = ws + (isv ? W_STRIDE : 0);
        const size_t c0 = (size_t)(t & (TPT - 1)) * TILE_F;
        float* dstb = out + (isv ? (size_t)LS * NELEM : (size_t)0);

        // C) Compute: all 28 outputs in this wave. acc = 28 VGPR.
        float acc[LS];
#pragma unroll
        for (int m = 0; m < LS; ++m) acc[m] = 0.f;

        do_lb<0>(wq, cur, lane, acc);
        do_lb<1>(wq, cur, lane, acc);
        do_lb<2>(wq, cur, lane, acc);
        do_lb<3>(wq, cur, lane, acc);
        do_lb<4>(wq, cur, lane, acc);
        do_lb<5>(wq, cur, lane, acc);
        do_lb<6>(wq, cur, lane, acc);
        do_lb<7>(wq, cur, lane, acc);
        do_lb<8>(wq, cur, lane, acc);

        // D) 28 coalesced dword stores (256 B each), fire-and-forget;
        //    they drain under the next tile's compute.
#pragma unroll
        for (int m = 0; m < LS; ++m)
            dstb[(size_t)m * NELEM + c0 + lane] = acc[m];

        if (!more) break;
        t = tn;
        float (*tmp)[TILE_F] = cur; cur = nxt; nxt = tmp;
    }
}

extern "C" void kernel_launch(void* const* d_in, const int* in_sizes, int n_in,
                              void* d_out, int out_size, void* d_ws, size_t ws_size,
                              hipStream_t stream)
{
    const float* ks  = (const float*)d_in[0];
    const float* vs  = (const float*)d_in[1];
    const float* lgk = (const float*)d_in[2];
    const float* lgv = (const float*)d_in[3];
    float* ws  = (float*)d_ws;     // 8064 B scratch for softmaxed weights
    float* out = (float*)d_out;

    hipLaunchKernelGGL(softmax_kernel, dim3(1), dim3(64), 0, stream,
                       lgk, lgv, ws);
    hipLaunchKernelGGL(pool_kernel, dim3(NBLOCKS), dim3(64), 0, stream,
                       ks, vs, ws, out);
}

// Round 11
// 232.552 us; speedup vs baseline: 1.0515x; 1.0515x over previous
//
#include <hip/hip_runtime.h>
#include <cstddef>

// AttentionLayerPooler: out[m,n] = sum_l softmax(logits)[m,l] * in[l,n]
// LT=36, LS=28, slice = 2,097,152 fp32.
//
// R5-R10 (five different on-chip structures) ALL land 230-245 us at
// ~3.1 TB/s HBM-view. Surviving invariant: every structure touches
// 36+28 streams in 256B-1KB fragments (stride 8 MB) -> DRAM page
// efficiency ~50%. fillBuffer (1 sequential stream) hits 6.8 TB/s at 11%
// occupancy on the same chip.
// R11: DRAM-contiguity restructure. Block owns a 2048-float chunk (8 KB);
// streams layer-by-layer: each layer read is ONE 8 KB contiguous run
// (1 global_load_lds per wave), acc = float4 acc[28] in registers
// (112 VGPR, R1-proven no-spill, NO launch_bounds min-waves), outputs
// written as 28 x 8 KB contiguous runs. Depth-3 LDS rotation (24 KB),
// wave-private segments -> ZERO barriers; counted vmcnt(2) ledger.
// Weights via R9/R10-proven SMEM s_load path, layout [l][m].

constexpr int LT = 36;
constexpr int LS = 28;
constexpr int NELEM = 2097152;          // floats per layer slice
constexpr int CHUNK = 2048;             // floats per layer per block (8 KB)
constexpr int NCHUNK = NELEM / CHUNK;   // 1024 chunks per tensor
constexpr int TPB = 512;                // 8 waves; thread owns 4 floats
constexpr int W_TSTRIDE = LS * LT;      // 1008 floats per weight table

typedef __attribute__((ext_vector_type(4))) float f32x4;

// Pre-kernel: softmax both 28x36 tables into d_ws, layout ws[t][l][m]
// (m contiguous): layer l's 28 weights at byte offset t*4032 + l*112,
// 16B-aligned -> 7 s_load_dwordx4 per layer.
__global__ __launch_bounds__(64) void softmax_kernel(
    const float* __restrict__ lgk, const float* __restrict__ lgv,
    float* __restrict__ ws)
{
    const int t = threadIdx.x;
    const int isv = t >> 5;
    const int m = t & 31;
    if (m >= LS) return;
    const float* row = (isv ? lgv : lgk) + m * LT;
    float mx = -3.4e38f;
    for (int l = 0; l < LT; ++l) mx = fmaxf(mx, row[l]);
    float s = 0.f;
    for (int l = 0; l < LT; ++l) s += expf(row[l] - mx);
    const float inv = 1.0f / s;
    float* o = ws + isv * W_TSTRIDE;
    for (int l = 0; l < LT; ++l) o[l * LS + m] = expf(row[l] - mx) * inv;
}

// One layer: 7 weight quads via SMEM (28 SGPRs, K$-hot), 112 FMAs.
// W[q][j] is weight for m = 4q+j; SGPR operand on v_fma is legal (1 SGPR).
__device__ __forceinline__ void layer_fma(const float* wlp, const float4 dv,
                                          float4* acc)
{
    f32x4 w0, w1, w2, w3, w4, w5, w6;
    asm volatile(
        "s_load_dwordx4 %0, %[b], %[o0]\n\t"
        "s_load_dwordx4 %1, %[b], %[o1]\n\t"
        "s_load_dwordx4 %2, %[b], %[o2]\n\t"
        "s_load_dwordx4 %3, %[b], %[o3]\n\t"
        "s_load_dwordx4 %4, %[b], %[o4]\n\t"
        "s_load_dwordx4 %5, %[b], %[o5]\n\t"
        "s_load_dwordx4 %6, %[b], %[o6]\n\t"
        "s_waitcnt lgkmcnt(0)"
        : "=s"(w0), "=s"(w1), "=s"(w2), "=s"(w3), "=s"(w4), "=s"(w5), "=s"(w6)
        : [b] "s"(wlp),
          [o0] "i"(0),  [o1] "i"(16), [o2] "i"(32), [o3] "i"(48),
          [o4] "i"(64), [o5] "i"(80), [o6] "i"(96));

    const f32x4 W[7] = {w0, w1, w2, w3, w4, w5, w6};
#pragma unroll
    for (int q = 0; q < 7; ++q) {
#pragma unroll
        for (int j = 0; j < 4; ++j) {
            const float w = W[q][j];
            float4& a = acc[4 * q + j];
            a.x = fmaf(w, dv.x, a.x);
            a.y = fmaf(w, dv.y, a.y);
            a.z = fmaf(w, dv.z, a.z);
            a.w = fmaf(w, dv.w, a.w);
        }
    }
}

__global__ __launch_bounds__(TPB) void pool_kernel(
    const float* __restrict__ ks,
    const float* __restrict__ vs,
    const float* __restrict__ ws,
    float* __restrict__ out)
{
    // Depth-3 rotation of 8 KB layer-chunks = 24 KB. Each wave DMAs and
    // reads ONLY its own 1 KB segment -> no cross-wave deps, no barriers.
    __shared__ float buf[3][CHUNK];

    const int tid  = threadIdx.x;
    const int wv   = tid >> 6;

    const int bid  = blockIdx.x;
    const bool isv = (bid >= NCHUNK);
    const float* src = isv ? vs : ks;
    const float* wl0 = ws + (isv ? W_TSTRIDE : 0);
    float* dstb = out + (isv ? (size_t)LS * NELEM : (size_t)0);
    const size_t cbase = (size_t)(bid & (NCHUNK - 1)) * CHUNK;
    const size_t toff  = cbase + (size_t)tid * 4;  // thread's 16 B in the run

    // Stage layer l's 8 KB contiguous run: ONE global_load_lds per wave.
    // LDS dest wave-uniform (&buf[d][wv*256]); HW adds lane*16 -> lane L
    // lands at floats (wv*64+L)*4 = exactly thread tid's segment.
    auto stage = [&](int d, int l) {
        const float* g = src + (size_t)l * NELEM + toff;
        __builtin_amdgcn_global_load_lds(
            (const __attribute__((address_space(1))) void*)g,
            (__attribute__((address_space(3))) void*)&buf[d][wv * 256],
            16, 0, 0);
    };

    stage(0, 0);
    stage(1, 1);

    float4 acc[LS];
#pragma unroll
    for (int m = 0; m < LS; ++m) acc[m] = make_float4(0.f, 0.f, 0.f, 0.f);

    // Main loop: issue load(l+2), wait for load(l) only (vmcnt(2): loads
    // l+1, l+2 stay in flight -> 2-3 KB/wave outstanding, 16-24 KB/CU).
    // LDS slot reuse is safe: slot (l+2)%3 was read at iter l-1, whose
    // ds_read was drained by layer_fma's lgkmcnt(0).
    for (int l = 0; l < LT - 2; ++l) {
        stage((l + 2) % 3, l + 2);
        asm volatile("s_waitcnt vmcnt(2)" ::: "memory");
        __builtin_amdgcn_sched_barrier(0);
        const float4 dv = *reinterpret_cast<const float4*>(&buf[l % 3][tid * 4]);
        layer_fma(wl0 + l * LS, dv, acc);
    }
    asm volatile("s_waitcnt vmcnt(1)" ::: "memory");
    __builtin_amdgcn_sched_barrier(0);
    {
        const float4 dv = *reinterpret_cast<const float4*>(&buf[(LT - 2) % 3][tid * 4]);
        layer_fma(wl0 + (LT - 2) * LS, dv, acc);
    }
    asm volatile("s_waitcnt vmcnt(0)" ::: "memory");
    __builtin_amdgcn_sched_barrier(0);
    {
        const float4 dv = *reinterpret_cast<const float4*>(&buf[(LT - 1) % 3][tid * 4]);
        layer_fma(wl0 + (LT - 1) * LS, dv, acc);
    }

    // 28 output streams, each written as one 8 KB contiguous run by the
    // block (dwordx4 per lane). Fire-and-forget; drains during the next
    // block's startup.
#pragma unroll
    for (int m = 0; m < LS; ++m) {
        float4* q = reinterpret_cast<float4*>(dstb + (size_t)m * NELEM + cbase);
        q[tid] = acc[m];
    }
}

extern "C" void kernel_launch(void* const* d_in, const int* in_sizes, int n_in,
                              void* d_out, int out_size, void* d_ws, size_t ws_size,
                              hipStream_t stream)
{
    const float* ks  = (const float*)d_in[0];
    const float* vs  = (const float*)d_in[1];
    const float* lgk = (const float*)d_in[2];
    const float* lgv = (const float*)d_in[3];
    float* ws  = (float*)d_ws;     // 8064 B scratch for softmaxed weights
    float* out = (float*)d_out;

    hipLaunchKernelGGL(softmax_kernel, dim3(1), dim3(64), 0, stream,
                       lgk, lgv, ws);
    hipLaunchKernelGGL(pool_kernel, dim3(2 * NCHUNK), dim3(TPB), 0, stream,
                       ks, vs, ws, out);
}